// Round 5
// baseline (777.294 us; speedup 1.0000x reference)
//
#include <hip/hip_runtime.h>

#define ENTITIES_N 100000
#define RELATIONS_N 1000
#define WIDTH (2 * ENTITIES_N + RELATIONS_N)   // 201000
#define BATCH_ROWS 1024                        // fixed by the problem (BATCH = 1024)

// Total output: 1024 * 201000 floats = 823,296,000 B = 51,456,000 float4s.
#define TOTAL_F4 (BATCH_ROWS * (WIDTH / 4))    // 51,456,000
#define FILL_BLOCK 256
#define FILL_GRID (TOTAL_F4 / FILL_BLOCK)      // 201,000 blocks, exact

// Native clang vector type — __builtin_nontemporal_store accepts these
// (it rejects HIP_vector_type<float,4>, which caused R4's compile failure).
typedef float f32x4 __attribute__((ext_vector_type(4)));

// R5 = R4 retry: store-and-exit shape + NON-TEMPORAL stores.
// Evidence trail: SDMA memset (3.3 TB/s), loop stores (2.8), store-and-exit
// (3.36) all plateau at ~half of fillBufferAligned's demonstrated 6.34 TB/s
// pure-write rate. 823 MB in 245 us with write-allocate line fills = 1.65 GB
// of HBM traffic = 6.7 TB/s combined — exactly the HBM ceiling. Theory: our
// plain stores pay a line-fill read per store; nt stores should elide it
// (harness fill's FETCH_SIZE ~= 0 proves eliding is possible).
__global__ __launch_bounds__(FILL_BLOCK) void zero_fill_nt(f32x4* __restrict__ out4) {
  const unsigned i = blockIdx.x * FILL_BLOCK + threadIdx.x;  // < 51.5M, fits u32
  f32x4 z = {0.0f, 0.0f, 0.0f, 0.0f};
  __builtin_nontemporal_store(z, &out4[i]);
}

// Tiny scatter: 3*1024 ones. h/r/t column segments are disjoint -> no conflicts.
__global__ void scatter_ones_i32(const int* __restrict__ hID,
                                 const int* __restrict__ rID,
                                 const int* __restrict__ tID,
                                 float* __restrict__ out) {
  int row = blockIdx.x * blockDim.x + threadIdx.x;
  if (row >= BATCH_ROWS) return;
  long long base = (long long)row * WIDTH;
  out[base + (long long)hID[row]] = 1.0f;
  out[base + ENTITIES_N + (long long)rID[row]] = 1.0f;
  out[base + ENTITIES_N + RELATIONS_N + (long long)tID[row]] = 1.0f;
}

__global__ void scatter_ones_i64(const long long* __restrict__ hID,
                                 const int* __restrict__ rID,
                                 const int* __restrict__ tID,
                                 float* __restrict__ out) {
  int row = blockIdx.x * blockDim.x + threadIdx.x;
  if (row >= BATCH_ROWS) return;
  long long base = (long long)row * WIDTH;
  out[base + hID[row]] = 1.0f;
  out[base + ENTITIES_N + (long long)rID[row]] = 1.0f;
  out[base + ENTITIES_N + RELATIONS_N + (long long)tID[row]] = 1.0f;
}

extern "C" void kernel_launch(void* const* d_in, const int* in_sizes, int n_in,
                              void* d_out, int out_size, void* d_ws, size_t ws_size,
                              hipStream_t stream) {
  // Inputs (setup_inputs order): z [B,128] f32 (unused), hID [B] int32/int64,
  // rID [B] i32, tID [B] i32.
  const int* rID = (const int*)d_in[2];
  const int* tID = (const int*)d_in[3];
  float* out = (float*)d_out;

  // 823 MB of zeros: store-and-exit shape (R3 best) + nt cache-bypass stores.
  zero_fill_nt<<<FILL_GRID, FILL_BLOCK, 0, stream>>>(reinterpret_cast<f32x4*>(out));

  // Then the 3*1024 ones (same stream serializes after the fill).
  const int block = 256;
  const int grid = (BATCH_ROWS + block - 1) / block;  // 4 workgroups
  if (in_sizes[1] == 2 * in_sizes[3]) {
    scatter_ones_i64<<<grid, block, 0, stream>>>((const long long*)d_in[1], rID, tID, out);
  } else {
    scatter_ones_i32<<<grid, block, 0, stream>>>((const int*)d_in[1], rID, tID, out);
  }
}